// Round 3
// baseline (208.992 us; speedup 1.0000x reference)
//
#include <hip/hip_runtime.h>
#include <math.h>

// Problem constants (from reference)
#define NROWS 84
#define SLEN  131072
#define BLOCKS_PER_ROW 16
#define THREADS 256
#define ITERS 8
// Segment per block = SLEN/16 = 8192 floats = 2048 float4.
// Per thread: 8 float4 from ST + 8 from W, software-pipelined (prefetch
// next round's pair while computing current) so each wave keeps >=4KB
// of loads in flight across its whole lifetime instead of stalling per pair.

__device__ __forceinline__ float sigw(float x, float b, float bias) {
    return __frcp_rn(1.0f + __expf(-b * (bias + x)));
}

__global__ __launch_bounds__(THREADS) void rowdot_kernel(
    const float* __restrict__ ST0, const float* __restrict__ W0,
    const float* __restrict__ ST1, const float* __restrict__ W1,
    const float* __restrict__ BEV, const float* __restrict__ BEV_p,
    const float* __restrict__ B, float* __restrict__ tmp /* 168 floats */)
{
    const int bid = blockIdx.x;
    const int tensor = (bid >= NROWS * BLOCKS_PER_ROW) ? 1 : 0;
    const int local  = bid - tensor * NROWS * BLOCKS_PER_ROW;
    const int row = local / BLOCKS_PER_ROW;
    const int seg = local % BLOCKS_PER_ROW;

    const float* __restrict__ STp = tensor ? ST1 : ST0;
    const float* __restrict__ Wp  = tensor ? W1  : W0;

    const float bias = fmaxf(BEV_p[0], 0.0f) * BEV[0];
    const float b    = B[0];

    const size_t base = (size_t)row * SLEN + (size_t)seg * (SLEN / BLOCKS_PER_ROW);
    const float4* __restrict__ st4 = (const float4*)(STp + base);
    const float4* __restrict__ w4  = (const float4*)(Wp + base);

    const int t = threadIdx.x;

    // ---- software pipeline: prefetch round i+1, compute round i ----
    float4 sc = st4[t];
    float4 wc = w4[t];

    float a0 = 0.f, a1 = 0.f, a2 = 0.f, a3 = 0.f;

#pragma unroll
    for (int i = 1; i < ITERS; ++i) {
        float4 sn = st4[t + i * THREADS];
        float4 wn = w4[t + i * THREADS];
        a0 += wc.x * sigw(sc.x, b, bias);
        a1 += wc.y * sigw(sc.y, b, bias);
        a2 += wc.z * sigw(sc.z, b, bias);
        a3 += wc.w * sigw(sc.w, b, bias);
        sc = sn; wc = wn;
    }
    a0 += wc.x * sigw(sc.x, b, bias);
    a1 += wc.y * sigw(sc.y, b, bias);
    a2 += wc.z * sigw(sc.z, b, bias);
    a3 += wc.w * sigw(sc.w, b, bias);

    float acc = (a0 + a1) + (a2 + a3);

    // wave-64 reduction
#pragma unroll
    for (int off = 32; off > 0; off >>= 1)
        acc += __shfl_down(acc, off, 64);

    __shared__ float sdata[THREADS / 64];
    if ((t & 63) == 0) sdata[t >> 6] = acc;
    __syncthreads();

    if (t == 0) {
        float ssum = 0.0f;
#pragma unroll
        for (int wv = 0; wv < THREADS / 64; ++wv) ssum += sdata[wv];
        atomicAdd(&tmp[tensor * NROWS + row], ssum);
    }
}

__global__ void finalize_kernel(
    const float* __restrict__ tmp,
    const float* __restrict__ p0, const float* __restrict__ p1,
    const float* __restrict__ p2, const float* __restrict__ p3,
    const float* __restrict__ p4, float* __restrict__ out)
{
    if (threadIdx.x != 0 || blockIdx.x != 0) return;

    const float* logits[5] = {p0, p1, p2, p3, p4};
    float total = 0.0f;

    for (int set = 0; set < 5; ++set) {
        const float* lg = logits[set];
        float m = fmaxf(fmaxf(lg[0], lg[1]), fmaxf(lg[2], lg[3]));
        float e[4], sum = 0.0f;
        for (int i = 0; i < 4; ++i) { e[i] = expf(lg[i] - m); sum += e[i]; }
        float p[4];
        for (int i = 0; i < 4; ++i) p[i] = e[i] / sum;

        const float* tv = (set == 0) ? tmp : tmp + NROWS;

        float dot = 0.0f;
        int idx = 0;
        for (int i = 0; i < 4; ++i) {
            dot += p[i] * tv[idx++];
            for (int j = 0; j < 4; ++j) {
                float pij = p[i] * p[j];
                dot += pij * tv[idx++];
                for (int k = 0; k < 4; ++k)
                    dot += pij * p[k] * tv[idx++];
            }
        }
        total += dot;
    }
    out[0] = total * 0.2f;  // mean of 5 vals
}

extern "C" void kernel_launch(void* const* d_in, const int* in_sizes, int n_in,
                              void* d_out, int out_size, void* d_ws, size_t ws_size,
                              hipStream_t stream) {
    const float* BEV   = (const float*)d_in[0];
    const float* ST0   = (const float*)d_in[1];
    const float* W0    = (const float*)d_in[2];
    const float* ST1   = (const float*)d_in[3];
    const float* W1    = (const float*)d_in[4];
    const float* p0    = (const float*)d_in[5];
    const float* p1    = (const float*)d_in[6];
    const float* p2    = (const float*)d_in[7];
    const float* p3    = (const float*)d_in[8];
    const float* p4    = (const float*)d_in[9];
    const float* BEV_p = (const float*)d_in[10];
    const float* B     = (const float*)d_in[11];

    float* tmp = (float*)d_ws;                 // 168 floats of partial row-dots
    float* out = (float*)d_out;

    hipMemsetAsync(tmp, 0, 2 * NROWS * sizeof(float), stream);

    const int grid = 2 * NROWS * BLOCKS_PER_ROW;  // 2688 blocks
    rowdot_kernel<<<grid, THREADS, 0, stream>>>(ST0, W0, ST1, W1, BEV, BEV_p, B, tmp);
    finalize_kernel<<<1, 64, 0, stream>>>(tmp, p0, p1, p2, p3, p4, out);
}

// Round 4
// 204.325 us; speedup vs baseline: 1.0228x; 1.0228x over previous
//
#include <hip/hip_runtime.h>
#include <math.h>

// Problem constants (from reference)
#define NROWS 84
#define SLEN  131072
#define BLOCKS_PER_ROW 16
#define THREADS 256
// Segment per block = SLEN/16 = 8192 floats = 2048 float4.
// 8 rounds/thread; each round = one float4 from ST + one from W.
// R1-R3 all compiled to the same VGPR=24 load->vmcnt(0)->use serial loop
// (compiler sinks/canonicalizes source-level pipelines). Here the loads are
// inline-asm global_load_dwordx4 with explicit s_waitcnt vmcnt(N), depth-4
// rotation -> 8 loads (8KB/wave) in flight, no barriers in the hot path.

typedef float f32x4 __attribute__((ext_vector_type(4)));

__device__ __forceinline__ float sigw(float x, float b, float bias) {
    return __frcp_rn(1.0f + __expf(-b * (bias + x)));
}

__global__ __launch_bounds__(THREADS) void rowdot_kernel(
    const float* __restrict__ ST0, const float* __restrict__ W0,
    const float* __restrict__ ST1, const float* __restrict__ W1,
    const float* __restrict__ BEV, const float* __restrict__ BEV_p,
    const float* __restrict__ B, float* __restrict__ tmp /* 168 floats */)
{
    const int bid = blockIdx.x;
    const int tensor = (bid >= NROWS * BLOCKS_PER_ROW) ? 1 : 0;
    const int local  = bid - tensor * NROWS * BLOCKS_PER_ROW;
    const int row = local / BLOCKS_PER_ROW;
    const int seg = local % BLOCKS_PER_ROW;

    const float* __restrict__ STp = tensor ? ST1 : ST0;
    const float* __restrict__ Wp  = tensor ? W1  : W0;

    const float bias = fmaxf(BEV_p[0], 0.0f) * BEV[0];
    const float b    = B[0];

    const size_t base = (size_t)row * SLEN + (size_t)seg * (SLEN / BLOCKS_PER_ROW);
    const int t = threadIdx.x;
    const f32x4* sp = (const f32x4*)(STp + base) + t;
    const f32x4* wp = (const f32x4*)(Wp  + base) + t;

    f32x4 s0, s1, s2, s3, w0, w1, w2, w3;
    float a0 = 0.f, a1 = 0.f, a2 = 0.f, a3 = 0.f;

    // Issue a round's two loads into a register slot (fire-and-forget;
    // compiler doesn't know these are loads, so it cannot serialize them).
#define ISSUE(i, ss, ww)                                                   \
    asm volatile("global_load_dwordx4 %0, %1, off"                         \
                 : "=v"(ss) : "v"(sp + (i) * THREADS));                    \
    asm volatile("global_load_dwordx4 %0, %1, off"                        \
                 : "=v"(ww) : "v"(wp + (i) * THREADS));

    // Wait until this slot's pair has landed. Tying the data regs with "+v"
    // pins consumer ordering after the wait.
#define WAITN(n, ss, ww)                                                   \
    asm volatile("s_waitcnt vmcnt(" #n ")" : "+v"(ss), "+v"(ww));

#define COMPUTE(ss, ww)                                                    \
    a0 += (ww).x * sigw((ss).x, b, bias);                                  \
    a1 += (ww).y * sigw((ss).y, b, bias);                                  \
    a2 += (ww).z * sigw((ss).z, b, bias);                                  \
    a3 += (ww).w * sigw((ss).w, b, bias);

    // Prologue: fill the pipe (rounds 0..3 -> 8 loads in flight)
    ISSUE(0, s0, w0) ISSUE(1, s1, w1) ISSUE(2, s2, w2) ISSUE(3, s3, w3)

    // Steady state: wait for oldest round, compute it, refill its slot.
    WAITN(6, s0, w0) COMPUTE(s0, w0) ISSUE(4, s0, w0)
    WAITN(6, s1, w1) COMPUTE(s1, w1) ISSUE(5, s1, w1)
    WAITN(6, s2, w2) COMPUTE(s2, w2) ISSUE(6, s2, w2)
    WAITN(6, s3, w3) COMPUTE(s3, w3) ISSUE(7, s3, w3)

    // Drain
    WAITN(6, s0, w0) COMPUTE(s0, w0)
    WAITN(4, s1, w1) COMPUTE(s1, w1)
    WAITN(2, s2, w2) COMPUTE(s2, w2)
    WAITN(0, s3, w3) COMPUTE(s3, w3)

#undef ISSUE
#undef WAITN
#undef COMPUTE

    float acc = (a0 + a1) + (a2 + a3);

    // wave-64 reduction
#pragma unroll
    for (int off = 32; off > 0; off >>= 1)
        acc += __shfl_down(acc, off, 64);

    __shared__ float sdata[THREADS / 64];
    if ((t & 63) == 0) sdata[t >> 6] = acc;
    __syncthreads();

    if (t == 0) {
        float ssum = 0.0f;
#pragma unroll
        for (int wv = 0; wv < THREADS / 64; ++wv) ssum += sdata[wv];
        atomicAdd(&tmp[tensor * NROWS + row], ssum);
    }
}

__global__ void finalize_kernel(
    const float* __restrict__ tmp,
    const float* __restrict__ p0, const float* __restrict__ p1,
    const float* __restrict__ p2, const float* __restrict__ p3,
    const float* __restrict__ p4, float* __restrict__ out)
{
    if (threadIdx.x != 0 || blockIdx.x != 0) return;

    const float* logits[5] = {p0, p1, p2, p3, p4};
    float total = 0.0f;

    for (int set = 0; set < 5; ++set) {
        const float* lg = logits[set];
        float m = fmaxf(fmaxf(lg[0], lg[1]), fmaxf(lg[2], lg[3]));
        float e[4], sum = 0.0f;
        for (int i = 0; i < 4; ++i) { e[i] = expf(lg[i] - m); sum += e[i]; }
        float p[4];
        for (int i = 0; i < 4; ++i) p[i] = e[i] / sum;

        const float* tv = (set == 0) ? tmp : tmp + NROWS;

        float dot = 0.0f;
        int idx = 0;
        for (int i = 0; i < 4; ++i) {
            dot += p[i] * tv[idx++];
            for (int j = 0; j < 4; ++j) {
                float pij = p[i] * p[j];
                dot += pij * tv[idx++];
                for (int k = 0; k < 4; ++k)
                    dot += pij * p[k] * tv[idx++];
            }
        }
        total += dot;
    }
    out[0] = total * 0.2f;  // mean of 5 vals
}

extern "C" void kernel_launch(void* const* d_in, const int* in_sizes, int n_in,
                              void* d_out, int out_size, void* d_ws, size_t ws_size,
                              hipStream_t stream) {
    const float* BEV   = (const float*)d_in[0];
    const float* ST0   = (const float*)d_in[1];
    const float* W0    = (const float*)d_in[2];
    const float* ST1   = (const float*)d_in[3];
    const float* W1    = (const float*)d_in[4];
    const float* p0    = (const float*)d_in[5];
    const float* p1    = (const float*)d_in[6];
    const float* p2    = (const float*)d_in[7];
    const float* p3    = (const float*)d_in[8];
    const float* p4    = (const float*)d_in[9];
    const float* BEV_p = (const float*)d_in[10];
    const float* B     = (const float*)d_in[11];

    float* tmp = (float*)d_ws;                 // 168 floats of partial row-dots
    float* out = (float*)d_out;

    hipMemsetAsync(tmp, 0, 2 * NROWS * sizeof(float), stream);

    const int grid = 2 * NROWS * BLOCKS_PER_ROW;  // 2688 blocks
    rowdot_kernel<<<grid, THREADS, 0, stream>>>(ST0, W0, ST1, W1, BEV, BEV_p, B, tmp);
    finalize_kernel<<<1, 64, 0, stream>>>(tmp, p0, p1, p2, p3, p4, out);
}

// Round 5
// 195.681 us; speedup vs baseline: 1.0680x; 1.0442x over previous
//
#include <hip/hip_runtime.h>
#include <math.h>

// Problem constants (from reference)
#define NROWS 84
#define SLEN  131072
#define BLOCKS_PER_ROW 16
#define THREADS 256
// R4 established: per-wave MLP (8 x dwordx4 in flight, hand-placed vmcnt)
// does NOT move the needle; delivered read BW is pinned at ~2.77 TB/s even
// when the whole 176 MB is Infinity-Cache-resident (timed replays show
// FETCH_SIZE ~ 0). R5 single-variable change: 'nt' (non-temporal) flag on
// the streaming loads to skip L1/L2 allocation on the miss path.

typedef float f32x4 __attribute__((ext_vector_type(4)));

__device__ __forceinline__ float sigw(float x, float b, float bias) {
    return __frcp_rn(1.0f + __expf(-b * (bias + x)));
}

__global__ __launch_bounds__(THREADS) void rowdot_kernel(
    const float* __restrict__ ST0, const float* __restrict__ W0,
    const float* __restrict__ ST1, const float* __restrict__ W1,
    const float* __restrict__ BEV, const float* __restrict__ BEV_p,
    const float* __restrict__ B, float* __restrict__ tmp /* 168 floats */)
{
    const int bid = blockIdx.x;
    const int tensor = (bid >= NROWS * BLOCKS_PER_ROW) ? 1 : 0;
    const int local  = bid - tensor * NROWS * BLOCKS_PER_ROW;
    const int row = local / BLOCKS_PER_ROW;
    const int seg = local % BLOCKS_PER_ROW;

    const float* __restrict__ STp = tensor ? ST1 : ST0;
    const float* __restrict__ Wp  = tensor ? W1  : W0;

    const float bias = fmaxf(BEV_p[0], 0.0f) * BEV[0];
    const float b    = B[0];

    const size_t base = (size_t)row * SLEN + (size_t)seg * (SLEN / BLOCKS_PER_ROW);
    const int t = threadIdx.x;
    const f32x4* sp = (const f32x4*)(STp + base) + t;
    const f32x4* wp = (const f32x4*)(Wp  + base) + t;

    f32x4 s0, s1, s2, s3, w0, w1, w2, w3;
    float a0 = 0.f, a1 = 0.f, a2 = 0.f, a3 = 0.f;

    // Non-temporal streaming loads: evict-first, no L1/L2 allocate.
#define ISSUE(i, ss, ww)                                                   \
    asm volatile("global_load_dwordx4 %0, %1, off nt"                      \
                 : "=v"(ss) : "v"(sp + (i) * THREADS));                    \
    asm volatile("global_load_dwordx4 %0, %1, off nt"                      \
                 : "=v"(ww) : "v"(wp + (i) * THREADS));

#define WAITN(n, ss, ww)                                                   \
    asm volatile("s_waitcnt vmcnt(" #n ")" : "+v"(ss), "+v"(ww));

#define COMPUTE(ss, ww)                                                    \
    a0 += (ww).x * sigw((ss).x, b, bias);                                  \
    a1 += (ww).y * sigw((ss).y, b, bias);                                  \
    a2 += (ww).z * sigw((ss).z, b, bias);                                  \
    a3 += (ww).w * sigw((ss).w, b, bias);

    // Prologue: fill the pipe (rounds 0..3 -> 8 loads in flight)
    ISSUE(0, s0, w0) ISSUE(1, s1, w1) ISSUE(2, s2, w2) ISSUE(3, s3, w3)

    // Steady state: wait for oldest round, compute it, refill its slot.
    WAITN(6, s0, w0) COMPUTE(s0, w0) ISSUE(4, s0, w0)
    WAITN(6, s1, w1) COMPUTE(s1, w1) ISSUE(5, s1, w1)
    WAITN(6, s2, w2) COMPUTE(s2, w2) ISSUE(6, s2, w2)
    WAITN(6, s3, w3) COMPUTE(s3, w3) ISSUE(7, s3, w3)

    // Drain
    WAITN(6, s0, w0) COMPUTE(s0, w0)
    WAITN(4, s1, w1) COMPUTE(s1, w1)
    WAITN(2, s2, w2) COMPUTE(s2, w2)
    WAITN(0, s3, w3) COMPUTE(s3, w3)

#undef ISSUE
#undef WAITN
#undef COMPUTE

    float acc = (a0 + a1) + (a2 + a3);

    // wave-64 reduction
#pragma unroll
    for (int off = 32; off > 0; off >>= 1)
        acc += __shfl_down(acc, off, 64);

    __shared__ float sdata[THREADS / 64];
    if ((t & 63) == 0) sdata[t >> 6] = acc;
    __syncthreads();

    if (t == 0) {
        float ssum = 0.0f;
#pragma unroll
        for (int wv = 0; wv < THREADS / 64; ++wv) ssum += sdata[wv];
        atomicAdd(&tmp[tensor * NROWS + row], ssum);
    }
}

__global__ void finalize_kernel(
    const float* __restrict__ tmp,
    const float* __restrict__ p0, const float* __restrict__ p1,
    const float* __restrict__ p2, const float* __restrict__ p3,
    const float* __restrict__ p4, float* __restrict__ out)
{
    if (threadIdx.x != 0 || blockIdx.x != 0) return;

    const float* logits[5] = {p0, p1, p2, p3, p4};
    float total = 0.0f;

    for (int set = 0; set < 5; ++set) {
        const float* lg = logits[set];
        float m = fmaxf(fmaxf(lg[0], lg[1]), fmaxf(lg[2], lg[3]));
        float e[4], sum = 0.0f;
        for (int i = 0; i < 4; ++i) { e[i] = expf(lg[i] - m); sum += e[i]; }
        float p[4];
        for (int i = 0; i < 4; ++i) p[i] = e[i] / sum;

        const float* tv = (set == 0) ? tmp : tmp + NROWS;

        float dot = 0.0f;
        int idx = 0;
        for (int i = 0; i < 4; ++i) {
            dot += p[i] * tv[idx++];
            for (int j = 0; j < 4; ++j) {
                float pij = p[i] * p[j];
                dot += pij * tv[idx++];
                for (int k = 0; k < 4; ++k)
                    dot += pij * p[k] * tv[idx++];
            }
        }
        total += dot;
    }
    out[0] = total * 0.2f;  // mean of 5 vals
}

extern "C" void kernel_launch(void* const* d_in, const int* in_sizes, int n_in,
                              void* d_out, int out_size, void* d_ws, size_t ws_size,
                              hipStream_t stream) {
    const float* BEV   = (const float*)d_in[0];
    const float* ST0   = (const float*)d_in[1];
    const float* W0    = (const float*)d_in[2];
    const float* ST1   = (const float*)d_in[3];
    const float* W1    = (const float*)d_in[4];
    const float* p0    = (const float*)d_in[5];
    const float* p1    = (const float*)d_in[6];
    const float* p2    = (const float*)d_in[7];
    const float* p3    = (const float*)d_in[8];
    const float* p4    = (const float*)d_in[9];
    const float* BEV_p = (const float*)d_in[10];
    const float* B     = (const float*)d_in[11];

    float* tmp = (float*)d_ws;                 // 168 floats of partial row-dots
    float* out = (float*)d_out;

    hipMemsetAsync(tmp, 0, 2 * NROWS * sizeof(float), stream);

    const int grid = 2 * NROWS * BLOCKS_PER_ROW;  // 2688 blocks
    rowdot_kernel<<<grid, THREADS, 0, stream>>>(ST0, W0, ST1, W1, BEV, BEV_p, B, tmp);
    finalize_kernel<<<1, 64, 0, stream>>>(tmp, p0, p1, p2, p3, p4, out);
}

// Round 6
// 194.267 us; speedup vs baseline: 1.0758x; 1.0073x over previous
//
#include <hip/hip_runtime.h>
#include <math.h>

// Problem constants (from reference)
#define NROWS 84
#define SLEN  131072
#define BLOCKS_PER_ROW 32
#define THREADS 256
// R5 result: 'nt' streaming loads cut rowdot 63.5 -> <=40.7 us (>=4.3 TB/s
// read). R6: finer block granularity (5376 blocks, depth-4 pure pipeline,
// 4KB/tensor/block) to shrink the block-churn tail, plus atomic-free
// reduction: each block writes its own tmp[bid] slot (no memset dispatch,
// no atomic serialization). finalize does the 5376->168->1 reduction.

typedef float f32x4 __attribute__((ext_vector_type(4)));

__device__ __forceinline__ float sigw(float x, float b, float bias) {
    return __frcp_rn(1.0f + __expf(-b * (bias + x)));
}

__global__ __launch_bounds__(THREADS) void rowdot_kernel(
    const float* __restrict__ ST0, const float* __restrict__ W0,
    const float* __restrict__ ST1, const float* __restrict__ W1,
    const float* __restrict__ BEV, const float* __restrict__ BEV_p,
    const float* __restrict__ B, float* __restrict__ tmp /* 5376 floats */)
{
    const int bid = blockIdx.x;
    const int tensor = (bid >= NROWS * BLOCKS_PER_ROW) ? 1 : 0;
    const int local  = bid - tensor * NROWS * BLOCKS_PER_ROW;
    const int row = local / BLOCKS_PER_ROW;
    const int seg = local % BLOCKS_PER_ROW;

    const float* __restrict__ STp = tensor ? ST1 : ST0;
    const float* __restrict__ Wp  = tensor ? W1  : W0;

    const float bias = fmaxf(BEV_p[0], 0.0f) * BEV[0];
    const float b    = B[0];

    const size_t base = (size_t)row * SLEN + (size_t)seg * (SLEN / BLOCKS_PER_ROW);
    const int t = threadIdx.x;
    const f32x4* sp = (const f32x4*)(STp + base) + t;
    const f32x4* wp = (const f32x4*)(Wp  + base) + t;

    f32x4 s0, s1, s2, s3, w0, w1, w2, w3;
    float a0 = 0.f, a1 = 0.f, a2 = 0.f, a3 = 0.f;

    // Non-temporal streaming loads (evict-first): the R5 win.
#define ISSUE(i, ss, ww)                                                   \
    asm volatile("global_load_dwordx4 %0, %1, off nt"                      \
                 : "=v"(ss) : "v"(sp + (i) * THREADS));                    \
    asm volatile("global_load_dwordx4 %0, %1, off nt"                      \
                 : "=v"(ww) : "v"(wp + (i) * THREADS));

#define WAITN(n, ss, ww)                                                   \
    asm volatile("s_waitcnt vmcnt(" #n ")" : "+v"(ss), "+v"(ww));

#define COMPUTE(ss, ww)                                                    \
    a0 += (ww).x * sigw((ss).x, b, bias);                                  \
    a1 += (ww).y * sigw((ss).y, b, bias);                                  \
    a2 += (ww).z * sigw((ss).z, b, bias);                                  \
    a3 += (ww).w * sigw((ss).w, b, bias);

    // Depth-4 pure pipeline: issue all 8 loads, then drain oldest-first.
    ISSUE(0, s0, w0) ISSUE(1, s1, w1) ISSUE(2, s2, w2) ISSUE(3, s3, w3)
    WAITN(6, s0, w0) COMPUTE(s0, w0)
    WAITN(4, s1, w1) COMPUTE(s1, w1)
    WAITN(2, s2, w2) COMPUTE(s2, w2)
    WAITN(0, s3, w3) COMPUTE(s3, w3)

#undef ISSUE
#undef WAITN
#undef COMPUTE

    float acc = (a0 + a1) + (a2 + a3);

    // wave-64 reduction
#pragma unroll
    for (int off = 32; off > 0; off >>= 1)
        acc += __shfl_down(acc, off, 64);

    __shared__ float sdata[THREADS / 64];
    if ((t & 63) == 0) sdata[t >> 6] = acc;
    __syncthreads();

    if (t == 0) {
        float ssum = 0.0f;
#pragma unroll
        for (int wv = 0; wv < THREADS / 64; ++wv) ssum += sdata[wv];
        tmp[bid] = ssum;   // private slot — no atomic, no init needed
    }
}

__global__ void finalize_kernel(
    const float* __restrict__ tmp,   /* 5376 block partials */
    const float* __restrict__ p0, const float* __restrict__ p1,
    const float* __restrict__ p2, const float* __restrict__ p3,
    const float* __restrict__ p4, float* __restrict__ out)
{
    __shared__ float rowsum[2 * NROWS];
    const int t = threadIdx.x;

    // tmp[bid], bid = (tensor*84 + row)*32 + seg  ->  thread t<168 sums
    // the 32 contiguous partials of logical row t.
    if (t < 2 * NROWS) {
        const float* p = tmp + t * BLOCKS_PER_ROW;
        float s = 0.0f;
#pragma unroll
        for (int i = 0; i < BLOCKS_PER_ROW; ++i) s += p[i];
        rowsum[t] = s;
    }
    __syncthreads();

    if (t == 0) {
        const float* logits[5] = {p0, p1, p2, p3, p4};
        float total = 0.0f;
        for (int set = 0; set < 5; ++set) {
            const float* lg = logits[set];
            float m = fmaxf(fmaxf(lg[0], lg[1]), fmaxf(lg[2], lg[3]));
            float e[4], sum = 0.0f;
            for (int i = 0; i < 4; ++i) { e[i] = expf(lg[i] - m); sum += e[i]; }
            float p[4];
            for (int i = 0; i < 4; ++i) p[i] = e[i] / sum;

            const float* tv = (set == 0) ? rowsum : rowsum + NROWS;

            float dot = 0.0f;
            int idx = 0;
            for (int i = 0; i < 4; ++i) {
                dot += p[i] * tv[idx++];
                for (int j = 0; j < 4; ++j) {
                    float pij = p[i] * p[j];
                    dot += pij * tv[idx++];
                    for (int k = 0; k < 4; ++k)
                        dot += pij * p[k] * tv[idx++];
                }
            }
            total += dot;
        }
        out[0] = total * 0.2f;  // mean of 5 vals
    }
}

extern "C" void kernel_launch(void* const* d_in, const int* in_sizes, int n_in,
                              void* d_out, int out_size, void* d_ws, size_t ws_size,
                              hipStream_t stream) {
    const float* BEV   = (const float*)d_in[0];
    const float* ST0   = (const float*)d_in[1];
    const float* W0    = (const float*)d_in[2];
    const float* ST1   = (const float*)d_in[3];
    const float* W1    = (const float*)d_in[4];
    const float* p0    = (const float*)d_in[5];
    const float* p1    = (const float*)d_in[6];
    const float* p2    = (const float*)d_in[7];
    const float* p3    = (const float*)d_in[8];
    const float* p4    = (const float*)d_in[9];
    const float* BEV_p = (const float*)d_in[10];
    const float* B     = (const float*)d_in[11];

    float* tmp = (float*)d_ws;                 // 5376 block partials
    float* out = (float*)d_out;

    const int grid = 2 * NROWS * BLOCKS_PER_ROW;  // 5376 blocks
    rowdot_kernel<<<grid, THREADS, 0, stream>>>(ST0, W0, ST1, W1, BEV, BEV_p, B, tmp);
    finalize_kernel<<<1, 256, 0, stream>>>(tmp, p0, p1, p2, p3, p4, out);
}